// Round 1
// baseline (501.040 us; speedup 1.0000x reference)
//
#include <hip/hip_runtime.h>
#include <hip/hip_bf16.h>

// Problem constants
#define B_    1024
#define NOBJ  128
#define RREL  32
#define DIM   512
#define MTOT  32768   // B_*RREL

typedef __bf16 bf16x8 __attribute__((ext_vector_type(8)));
typedef float  f32x4  __attribute__((ext_vector_type(4)));

__device__ __forceinline__ unsigned short f2bf(float f) {
    unsigned int u = __float_as_uint(f);
    u += 0x7FFFu + ((u >> 16) & 1u);           // round-to-nearest-even
    return (unsigned short)(u >> 16);
}
__device__ __forceinline__ float bf2f(unsigned short h) {
    return __uint_as_float(((unsigned int)h) << 16);
}

__device__ __forceinline__ void load16_to_lds(const unsigned short* g, unsigned short* l) {
    // each lane copies 16B; LDS dest = wave-uniform base + lane*16
    __builtin_amdgcn_global_load_lds((const __attribute__((address_space(1))) void*)g,
                                     (__attribute__((address_space(3))) void*)l,
                                     16, 0, 0);
}

// ---------------------------------------------------------------------------
// Kernel 0: gather rows per relation, emit As=[s;o] bf16 (M x 1024) and
// Msum = bf16(s+o or s) (M x 512).
// ---------------------------------------------------------------------------
__global__ __launch_bounds__(256) void gather_kernel(
        const float* __restrict__ obj, const int* __restrict__ pairs,
        unsigned short* __restrict__ As, unsigned short* __restrict__ Msum) {
    int t = threadIdx.x;
    int base = blockIdx.x * 8;
    for (int rr = 0; rr < 8; ++rr) {
        int m  = base + rr;            // relation index
        int b  = m >> 5;
        int p0 = pairs[(m << 1) + 0];
        int p1 = pairs[(m << 1) + 1];
        const float* srow = obj + (size_t)(b * NOBJ + p0) * DIM;
        const float* orow = obj + (size_t)(b * NOBJ + p1) * DIM;
        float2 s2 = *(const float2*)(srow + 2 * t);
        float2 o2 = *(const float2*)(orow + 2 * t);
        size_t arow = (size_t)m * 1024;
        *(ushort2*)(As + arow + 2 * t)       = make_ushort2(f2bf(s2.x), f2bf(s2.y));
        *(ushort2*)(As + arow + DIM + 2 * t) = make_ushort2(f2bf(o2.x), f2bf(o2.y));
        float mx = s2.x, my = s2.y;
        if (p0 != p1) { mx += o2.x; my += o2.y; }
        *(ushort2*)(Msum + (size_t)m * DIM + 2 * t) = make_ushort2(f2bf(mx), f2bf(my));
    }
}

// ---------------------------------------------------------------------------
// Weight prep: f32 (K x N) -> bf16 (N x K)   (N is a power of two)
// ---------------------------------------------------------------------------
__global__ __launch_bounds__(256) void transpose_w(
        const float* __restrict__ in, unsigned short* __restrict__ out,
        int K, int Nlog2) {
    int id = blockIdx.x * 256 + threadIdx.x;
    if (id >= (K << Nlog2)) return;
    int k = id >> Nlog2;
    int n = id & ((1 << Nlog2) - 1);
    out[(size_t)n * K + k] = f2bf(in[id]);
}

// ---------------------------------------------------------------------------
// m97-style bf16 GEMM: C[M,N] = A[M,K] @ BT[N,K]^T + bias (+opt relu, +opt add)
// 128x128 block tile, 4 waves in 2x2, each wave 64x64 via 4x4 mfma 16x16x32.
// ---------------------------------------------------------------------------
template<bool RELU, bool ADD, bool OUT_BF16>
__global__ __launch_bounds__(256) void gemm_bt(
        const unsigned short* __restrict__ A, const unsigned short* __restrict__ BT,
        const float* __restrict__ bias, const float* __restrict__ addsrc,
        void* __restrict__ outp, int KTOT, int NTOT) {
    __shared__ __align__(16) unsigned short ldsA[128 * 32];
    __shared__ __align__(16) unsigned short ldsB[128 * 32];

    int tid  = threadIdx.x;
    int wid  = tid >> 6;
    int lane = tid & 63;
    int wm   = wid & 1;        // wave row (0..1)
    int wn   = wid >> 1;       // wave col (0..1)
    int m0   = blockIdx.x * 128;
    int n0   = blockIdx.y * 128;

    f32x4 acc[4][4];
    for (int i = 0; i < 4; ++i)
        for (int j = 0; j < 4; ++j)
            for (int k = 0; k < 4; ++k) acc[i][j][k] = 0.0f;

    int r = tid >> 2, c = tid & 3;    // staging: row in tile, 16B chunk
    const unsigned short* ag0 = A  + (size_t)(m0 + r)      * KTOT + c * 8;
    const unsigned short* ag1 = A  + (size_t)(m0 + 64 + r) * KTOT + c * 8;
    const unsigned short* bg0 = BT + (size_t)(n0 + r)      * KTOT + c * 8;
    const unsigned short* bg1 = BT + (size_t)(n0 + 64 + r) * KTOT + c * 8;
    unsigned short* la0 = ldsA + wid * 512;          // lane*16B appended by HW
    unsigned short* la1 = ldsA + 2048 + wid * 512;
    unsigned short* lb0 = ldsB + wid * 512;
    unsigned short* lb1 = ldsB + 2048 + wid * 512;

    int arow = wm * 64 + (lane & 15);     // + i*16
    int brow = wn * 64 + (lane & 15);     // + j*16
    int koff = (lane >> 4) * 8;

    for (int k0 = 0; k0 < KTOT; k0 += 32) {
        __syncthreads();                  // protect LDS from overwrite
        load16_to_lds(ag0 + k0, la0);
        load16_to_lds(ag1 + k0, la1);
        load16_to_lds(bg0 + k0, lb0);
        load16_to_lds(bg1 + k0, lb1);
        __syncthreads();                  // drains vmcnt before barrier

        bf16x8 a[4], b[4];
#pragma unroll
        for (int i = 0; i < 4; ++i)
            a[i] = *(const bf16x8*)(ldsA + (arow + i * 16) * 32 + koff);
#pragma unroll
        for (int j = 0; j < 4; ++j)
            b[j] = *(const bf16x8*)(ldsB + (brow + j * 16) * 32 + koff);
#pragma unroll
        for (int i = 0; i < 4; ++i)
#pragma unroll
            for (int j = 0; j < 4; ++j)
                acc[i][j] = __builtin_amdgcn_mfma_f32_16x16x32_bf16(a[i], b[j], acc[i][j], 0, 0, 0);
    }

    // epilogue: C/D layout col = lane&15, row = (lane>>4)*4 + reg  [m89/m91]
    int crow  = wm * 64 + (lane >> 4) * 4;
    int ccol0 = wn * 64 + (lane & 15);
    float bcol[4];
#pragma unroll
    for (int j = 0; j < 4; ++j) bcol[j] = bias[n0 + ccol0 + j * 16];

#pragma unroll
    for (int i = 0; i < 4; ++i) {
#pragma unroll
        for (int j = 0; j < 4; ++j) {
            int col = n0 + ccol0 + j * 16;
#pragma unroll
            for (int jj = 0; jj < 4; ++jj) {
                int row = m0 + crow + i * 16 + jj;
                float v = acc[i][j][jj] + bcol[j];
                if (RELU) v = fmaxf(v, 0.0f);
                if (ADD)  v += addsrc[(size_t)row * NTOT + col];
                if (OUT_BF16)
                    ((unsigned short*)outp)[(size_t)row * NTOT + col] = f2bf(v);
                else
                    ((float*)outp)[(size_t)row * NTOT + col] = v;
            }
        }
    }
}

// ---------------------------------------------------------------------------
// Head: logits = h2 @ fc3_w + b  (K=128, C=7), softmax, f32 out.
// One thread per relation; fc3_w staged in LDS.
// ---------------------------------------------------------------------------
__global__ __launch_bounds__(256) void head_kernel(
        const unsigned short* __restrict__ h2, const float* __restrict__ w3,
        const float* __restrict__ b3, float* __restrict__ out) {
    __shared__ float w[128 * 7];
    __shared__ float bb[7];
    int t = threadIdx.x;
    for (int i = t; i < 128 * 7; i += 256) w[i] = w3[i];
    if (t < 7) bb[t] = b3[t];
    __syncthreads();

    int m = blockIdx.x * 256 + t;
    const uint2* hv = (const uint2*)(h2 + (size_t)m * 128);
    float accv[7];
#pragma unroll
    for (int cc = 0; cc < 7; ++cc) accv[cc] = bb[cc];
    for (int kk = 0; kk < 32; ++kk) {
        uint2 u = hv[kk];
        float f0 = bf2f((unsigned short)(u.x & 0xffff));
        float f1 = bf2f((unsigned short)(u.x >> 16));
        float f2 = bf2f((unsigned short)(u.y & 0xffff));
        float f3 = bf2f((unsigned short)(u.y >> 16));
        int k = kk * 4;
#pragma unroll
        for (int cc = 0; cc < 7; ++cc) {
            accv[cc] = fmaf(f0, w[(k + 0) * 7 + cc], accv[cc]);
            accv[cc] = fmaf(f1, w[(k + 1) * 7 + cc], accv[cc]);
            accv[cc] = fmaf(f2, w[(k + 2) * 7 + cc], accv[cc]);
            accv[cc] = fmaf(f3, w[(k + 3) * 7 + cc], accv[cc]);
        }
    }
    float mx = accv[0];
#pragma unroll
    for (int cc = 1; cc < 7; ++cc) mx = fmaxf(mx, accv[cc]);
    float sum = 0.f;
#pragma unroll
    for (int cc = 0; cc < 7; ++cc) { accv[cc] = expf(accv[cc] - mx); sum += accv[cc]; }
    float inv = 1.0f / sum;
#pragma unroll
    for (int cc = 0; cc < 7; ++cc) out[(size_t)m * 7 + cc] = accv[cc] * inv;
}

// ---------------------------------------------------------------------------
extern "C" void kernel_launch(void* const* d_in, const int* in_sizes, int n_in,
                              void* d_out, int out_size, void* d_ws, size_t ws_size,
                              hipStream_t stream) {
    (void)in_sizes; (void)n_in; (void)out_size; (void)ws_size;
    const float* obj    = (const float*)d_in[0];
    const int*   pairs  = (const int*)  d_in[1];
    const float* fuse_w = (const float*)d_in[2];
    const float* fuse_b = (const float*)d_in[3];
    const float* gcn_w  = (const float*)d_in[4];
    const float* gcn_b  = (const float*)d_in[5];
    const float* fc1_w  = (const float*)d_in[6];
    const float* fc1_b  = (const float*)d_in[7];
    const float* fc2_w  = (const float*)d_in[8];
    const float* fc2_b  = (const float*)d_in[9];
    const float* fc3_w  = (const float*)d_in[10];
    const float* fc3_b  = (const float*)d_in[11];
    float* out = (float*)d_out;

    char* ws = (char*)d_ws;
    // Region A (64 MB): As during stages 0-1; h1/h2/rf afterwards.
    unsigned short* As      = (unsigned short*)(ws);                         // 64 MB
    unsigned short* h1      = (unsigned short*)(ws);                         // 16 MB
    unsigned short* h2      = (unsigned short*)(ws + (16u << 20));           //  8 MB
    unsigned short* rf      = (unsigned short*)(ws + (24u << 20));           // 32 MB
    unsigned short* Msum    = (unsigned short*)(ws + (64u << 20));           // 32 MB
    float*          initrel = (float*)         (ws + (96u << 20));           // 64 MB
    unsigned short* WfT     = (unsigned short*)(ws + (160u << 20));          //  1 MB
    unsigned short* WgT     = (unsigned short*)(ws + (161u << 20));          // 512 KB
    unsigned short* W1T     = (unsigned short*)(ws + (162u << 20));          // 256 KB
    unsigned short* W2T     = (unsigned short*)(ws + (163u << 20));          //  64 KB

    // Stage 0: gathers + weight prep
    gather_kernel<<<MTOT / 8, 256, 0, stream>>>(obj, pairs, As, Msum);
    transpose_w<<<(1024 * 512) / 256, 256, 0, stream>>>(fuse_w, WfT, 1024, 9);
    transpose_w<<<(512  * 512) / 256, 256, 0, stream>>>(gcn_w,  WgT, 512,  9);
    transpose_w<<<(512  * 256) / 256, 256, 0, stream>>>(fc1_w,  W1T, 512,  8);
    transpose_w<<<(256  * 128) / 256, 256, 0, stream>>>(fc2_w,  W2T, 256,  7);

    // Stage 1: init_rel = As @ fuse_w + fuse_b        (f32 out)
    gemm_bt<false, false, false><<<dim3(MTOT / 128, 4), 256, 0, stream>>>(
        As, WfT, fuse_b, nullptr, initrel, 1024, 512);
    // Stage 2: rf = relu(Msum @ gcn_w + gcn_b) + init_rel   (bf16 out)
    gemm_bt<true, true, true><<<dim3(MTOT / 128, 4), 256, 0, stream>>>(
        Msum, WgT, gcn_b, initrel, rf, 512, 512);
    // Stage 3: h1 = relu(rf @ fc1_w + fc1_b)
    gemm_bt<true, false, true><<<dim3(MTOT / 128, 2), 256, 0, stream>>>(
        rf, W1T, fc1_b, nullptr, h1, 512, 256);
    // Stage 4: h2 = relu(h1 @ fc2_w + fc2_b)
    gemm_bt<true, false, true><<<dim3(MTOT / 128, 1), 256, 0, stream>>>(
        h1, W2T, fc2_b, nullptr, h2, 256, 128);
    // Stage 5: logits + softmax
    head_kernel<<<MTOT / 256, 256, 0, stream>>>(h2, fc3_w, fc3_b, out);
}

// Round 2
// 470.209 us; speedup vs baseline: 1.0656x; 1.0656x over previous
//
#include <hip/hip_runtime.h>
#include <hip/hip_bf16.h>

// Problem constants
#define B_    1024
#define NOBJ  128
#define RREL  32
#define DIM   512
#define MTOT  32768   // B_*RREL

typedef __bf16 bf16x8 __attribute__((ext_vector_type(8)));
typedef float  f32x4  __attribute__((ext_vector_type(4)));

__device__ __forceinline__ unsigned short f2bf(float f) {
    unsigned int u = __float_as_uint(f);
    u += 0x7FFFu + ((u >> 16) & 1u);           // round-to-nearest-even
    return (unsigned short)(u >> 16);
}
__device__ __forceinline__ float bf2f(unsigned short h) {
    return __uint_as_float(((unsigned int)h) << 16);
}

__device__ __forceinline__ void load16_to_lds(const unsigned short* g, unsigned short* l) {
    // each lane copies 16B; LDS dest = wave-uniform base + lane*16
    __builtin_amdgcn_global_load_lds((const __attribute__((address_space(1))) void*)g,
                                     (__attribute__((address_space(3))) void*)l,
                                     16, 0, 0);
}

// ---------------------------------------------------------------------------
// Kernel 0: gather rows per relation, emit As=[s;o] bf16 (M x 1024) and
// Msum = bf16(s+o or s) (M x 512).
// ---------------------------------------------------------------------------
__global__ __launch_bounds__(256) void gather_kernel(
        const float* __restrict__ obj, const int* __restrict__ pairs,
        unsigned short* __restrict__ As, unsigned short* __restrict__ Msum) {
    int t = threadIdx.x;
    int base = blockIdx.x * 8;
    for (int rr = 0; rr < 8; ++rr) {
        int m  = base + rr;            // relation index
        int b  = m >> 5;
        int p0 = pairs[(m << 1) + 0];
        int p1 = pairs[(m << 1) + 1];
        const float* srow = obj + (size_t)(b * NOBJ + p0) * DIM;
        const float* orow = obj + (size_t)(b * NOBJ + p1) * DIM;
        float2 s2 = *(const float2*)(srow + 2 * t);
        float2 o2 = *(const float2*)(orow + 2 * t);
        size_t arow = (size_t)m * 1024;
        *(ushort2*)(As + arow + 2 * t)       = make_ushort2(f2bf(s2.x), f2bf(s2.y));
        *(ushort2*)(As + arow + DIM + 2 * t) = make_ushort2(f2bf(o2.x), f2bf(o2.y));
        float mx = s2.x, my = s2.y;
        if (p0 != p1) { mx += o2.x; my += o2.y; }
        *(ushort2*)(Msum + (size_t)m * DIM + 2 * t) = make_ushort2(f2bf(mx), f2bf(my));
    }
}

// ---------------------------------------------------------------------------
// Weight prep: f32 (K x N) -> bf16 (N x K), 32x32 LDS tile (coalesced both ways)
// ---------------------------------------------------------------------------
__global__ __launch_bounds__(256) void transpose_tile(
        const float* __restrict__ in, unsigned short* __restrict__ out,
        int K, int N) {
    __shared__ float t32[32][33];
    int t  = threadIdx.x;
    int tx = t & 31, ty = t >> 5;            // 32 x 8
    int bk = blockIdx.x * 32, bn = blockIdx.y * 32;
#pragma unroll
    for (int i = 0; i < 4; ++i)
        t32[ty + i * 8][tx] = in[(size_t)(bk + ty + i * 8) * N + bn + tx];
    __syncthreads();
#pragma unroll
    for (int i = 0; i < 4; ++i)
        out[(size_t)(bn + ty + i * 8) * K + bk + tx] = f2bf(t32[tx][ty + i * 8]);
}

// ---------------------------------------------------------------------------
// Fused stages 1+2:
//   rf = relu(Msum @ gcn_w + gcn_b) + (As @ fuse_w + fuse_b)   -> bf16 (M x 512)
// m97 structure: 128x128 tile, 4 waves 2x2, 4x4 mfma 16x16x32 per wave,
// two accumulator sets (fuse: K=1024, gcn: K=512).
// ---------------------------------------------------------------------------
__global__ __launch_bounds__(256) void gemm_fused12(
        const unsigned short* __restrict__ As,   // M x 1024
        const unsigned short* __restrict__ Msum, // M x 512
        const unsigned short* __restrict__ WfT,  // 512 x 1024 (N x K)
        const unsigned short* __restrict__ WgT,  // 512 x 512
        const float* __restrict__ fuse_b, const float* __restrict__ gcn_b,
        unsigned short* __restrict__ rf) {
    __shared__ __align__(16) unsigned short ldsA[128 * 32];
    __shared__ __align__(16) unsigned short ldsB[128 * 32];

    int tid  = threadIdx.x;
    int wid  = tid >> 6;
    int lane = tid & 63;
    int wm   = wid & 1;
    int wn   = wid >> 1;
    int m0   = blockIdx.x * 128;
    int n0   = blockIdx.y * 128;

    f32x4 accF[4][4], accG[4][4];
#pragma unroll
    for (int i = 0; i < 4; ++i)
#pragma unroll
        for (int j = 0; j < 4; ++j)
#pragma unroll
            for (int k = 0; k < 4; ++k) { accF[i][j][k] = 0.0f; accG[i][j][k] = 0.0f; }

    int r = tid >> 2, c = tid & 3;
    unsigned short* la0 = ldsA + wid * 512;
    unsigned short* la1 = ldsA + 2048 + wid * 512;
    unsigned short* lb0 = ldsB + wid * 512;
    unsigned short* lb1 = ldsB + 2048 + wid * 512;

    int arow = wm * 64 + (lane & 15);
    int brow = wn * 64 + (lane & 15);
    int koff = (lane >> 4) * 8;

    // ---- phase A: fuse GEMM, K=1024 ----
    {
        const unsigned short* ag0 = As + (size_t)(m0 + r)      * 1024 + c * 8;
        const unsigned short* ag1 = As + (size_t)(m0 + 64 + r) * 1024 + c * 8;
        const unsigned short* bg0 = WfT + (size_t)(n0 + r)      * 1024 + c * 8;
        const unsigned short* bg1 = WfT + (size_t)(n0 + 64 + r) * 1024 + c * 8;
        for (int k0 = 0; k0 < 1024; k0 += 32) {
            __syncthreads();
            load16_to_lds(ag0 + k0, la0);
            load16_to_lds(ag1 + k0, la1);
            load16_to_lds(bg0 + k0, lb0);
            load16_to_lds(bg1 + k0, lb1);
            __syncthreads();
            bf16x8 a[4], b[4];
#pragma unroll
            for (int i = 0; i < 4; ++i)
                a[i] = *(const bf16x8*)(ldsA + (arow + i * 16) * 32 + koff);
#pragma unroll
            for (int j = 0; j < 4; ++j)
                b[j] = *(const bf16x8*)(ldsB + (brow + j * 16) * 32 + koff);
#pragma unroll
            for (int i = 0; i < 4; ++i)
#pragma unroll
                for (int j = 0; j < 4; ++j)
                    accF[i][j] = __builtin_amdgcn_mfma_f32_16x16x32_bf16(a[i], b[j], accF[i][j], 0, 0, 0);
        }
    }
    // ---- phase B: gcn GEMM, K=512 ----
    {
        const unsigned short* ag0 = Msum + (size_t)(m0 + r)      * 512 + c * 8;
        const unsigned short* ag1 = Msum + (size_t)(m0 + 64 + r) * 512 + c * 8;
        const unsigned short* bg0 = WgT + (size_t)(n0 + r)      * 512 + c * 8;
        const unsigned short* bg1 = WgT + (size_t)(n0 + 64 + r) * 512 + c * 8;
        for (int k0 = 0; k0 < 512; k0 += 32) {
            __syncthreads();
            load16_to_lds(ag0 + k0, la0);
            load16_to_lds(ag1 + k0, la1);
            load16_to_lds(bg0 + k0, lb0);
            load16_to_lds(bg1 + k0, lb1);
            __syncthreads();
            bf16x8 a[4], b[4];
#pragma unroll
            for (int i = 0; i < 4; ++i)
                a[i] = *(const bf16x8*)(ldsA + (arow + i * 16) * 32 + koff);
#pragma unroll
            for (int j = 0; j < 4; ++j)
                b[j] = *(const bf16x8*)(ldsB + (brow + j * 16) * 32 + koff);
#pragma unroll
            for (int i = 0; i < 4; ++i)
#pragma unroll
                for (int j = 0; j < 4; ++j)
                    accG[i][j] = __builtin_amdgcn_mfma_f32_16x16x32_bf16(a[i], b[j], accG[i][j], 0, 0, 0);
        }
    }

    // epilogue: C/D layout col = lane&15, row = (lane>>4)*4 + reg
    int crow  = wm * 64 + (lane >> 4) * 4;
    int ccol0 = wn * 64 + (lane & 15);
    float bf_[4], bg_[4];
#pragma unroll
    for (int j = 0; j < 4; ++j) {
        bf_[j] = fuse_b[n0 + ccol0 + j * 16];
        bg_[j] = gcn_b [n0 + ccol0 + j * 16];
    }
#pragma unroll
    for (int i = 0; i < 4; ++i)
#pragma unroll
        for (int j = 0; j < 4; ++j) {
            int col = n0 + ccol0 + j * 16;
#pragma unroll
            for (int jj = 0; jj < 4; ++jj) {
                int row = m0 + crow + i * 16 + jj;
                float v = fmaxf(accG[i][j][jj] + bg_[j], 0.0f) + accF[i][j][jj] + bf_[j];
                rf[(size_t)row * 512 + col] = f2bf(v);
            }
        }
}

// ---------------------------------------------------------------------------
// Fused tail: h1 = relu(rf@W1+b1); h2 = relu(h1@W2+b2); out = softmax(h2@W3+b3)
// Block = 128 rows. Per n-tile (2 x 128 cols of h1): fc1 GEMM -> ldsH1,
// then fc2 partial accumulation (A from ldsH1, persistent acc2).
// Then h2 -> ldsH2, per-row head. LDS strides padded to 136 (2-way = free).
// ---------------------------------------------------------------------------
#define H1S 136
__global__ __launch_bounds__(256) void tail_kernel(
        const unsigned short* __restrict__ rf,   // M x 512
        const unsigned short* __restrict__ W1T,  // 256 x 512 (N x K)
        const unsigned short* __restrict__ W2T,  // 128 x 256
        const float* __restrict__ b1, const float* __restrict__ b2,
        const float* __restrict__ w3, const float* __restrict__ b3,
        float* __restrict__ out) {
    __shared__ __align__(16) unsigned short ldsA[128 * 32];
    __shared__ __align__(16) unsigned short ldsB[128 * 32];
    __shared__ __align__(16) unsigned short ldsH1[128 * H1S];
    __shared__ __align__(16) unsigned short ldsH2[128 * H1S];
    __shared__ float ldsW3[128 * 7];
    __shared__ float ldsB3[7];

    int tid  = threadIdx.x;
    int wid  = tid >> 6;
    int lane = tid & 63;
    int wm   = wid & 1;
    int wn   = wid >> 1;
    int m0   = blockIdx.x * 128;

    for (int i = tid; i < 128 * 7; i += 256) ldsW3[i] = w3[i];
    if (tid < 7) ldsB3[tid] = b3[tid];

    int r = tid >> 2, c = tid & 3;
    unsigned short* la0 = ldsA + wid * 512;
    unsigned short* la1 = ldsA + 2048 + wid * 512;
    unsigned short* lb0 = ldsB + wid * 512;
    unsigned short* lb1 = ldsB + 2048 + wid * 512;

    int arow = wm * 64 + (lane & 15);
    int brow = wn * 64 + (lane & 15);
    int koff = (lane >> 4) * 8;
    int crow  = wm * 64 + (lane >> 4) * 4;
    int ccol0 = wn * 64 + (lane & 15);

    const unsigned short* ag0 = rf + (size_t)(m0 + r)      * 512 + c * 8;
    const unsigned short* ag1 = rf + (size_t)(m0 + 64 + r) * 512 + c * 8;

    f32x4 acc2[4][4];
#pragma unroll
    for (int i = 0; i < 4; ++i)
#pragma unroll
        for (int j = 0; j < 4; ++j)
#pragma unroll
            for (int k = 0; k < 4; ++k) acc2[i][j][k] = 0.0f;

    for (int nt = 0; nt < 2; ++nt) {
        int n0 = nt * 128;
        // ---- fc1 GEMM for this n-tile: K=512 ----
        f32x4 acc1[4][4];
#pragma unroll
        for (int i = 0; i < 4; ++i)
#pragma unroll
            for (int j = 0; j < 4; ++j)
#pragma unroll
                for (int k = 0; k < 4; ++k) acc1[i][j][k] = 0.0f;

        const unsigned short* bg0 = W1T + (size_t)(n0 + r)      * 512 + c * 8;
        const unsigned short* bg1 = W1T + (size_t)(n0 + 64 + r) * 512 + c * 8;
        for (int k0 = 0; k0 < 512; k0 += 32) {
            __syncthreads();
            load16_to_lds(ag0 + k0, la0);
            load16_to_lds(ag1 + k0, la1);
            load16_to_lds(bg0 + k0, lb0);
            load16_to_lds(bg1 + k0, lb1);
            __syncthreads();
            bf16x8 a[4], b[4];
#pragma unroll
            for (int i = 0; i < 4; ++i)
                a[i] = *(const bf16x8*)(ldsA + (arow + i * 16) * 32 + koff);
#pragma unroll
            for (int j = 0; j < 4; ++j)
                b[j] = *(const bf16x8*)(ldsB + (brow + j * 16) * 32 + koff);
#pragma unroll
            for (int i = 0; i < 4; ++i)
#pragma unroll
                for (int j = 0; j < 4; ++j)
                    acc1[i][j] = __builtin_amdgcn_mfma_f32_16x16x32_bf16(a[i], b[j], acc1[i][j], 0, 0, 0);
        }
        // epilogue fc1 -> ldsH1 (relu + bias), local col 0..127
        __syncthreads();    // everyone done reading ldsA/ldsB of last iter
#pragma unroll
        for (int i = 0; i < 4; ++i)
#pragma unroll
            for (int j = 0; j < 4; ++j) {
                int col = ccol0 + j * 16;
                float bb = b1[n0 + col];
#pragma unroll
                for (int jj = 0; jj < 4; ++jj) {
                    int row = crow + i * 16 + jj;
                    float v = fmaxf(acc1[i][j][jj] + bb, 0.0f);
                    ldsH1[row * H1S + col] = f2bf(v);
                }
            }
        __syncthreads();
        // ---- fc2 partial: K-chunk = this n-tile's 128 cols ----
        const unsigned short* wg0 = W2T + (size_t)r        * 256 + n0 + c * 8;
        const unsigned short* wg1 = W2T + (size_t)(64 + r) * 256 + n0 + c * 8;
        for (int k0 = 0; k0 < 128; k0 += 32) {
            __syncthreads();
            load16_to_lds(wg0 + k0, lb0);
            load16_to_lds(wg1 + k0, lb1);
            __syncthreads();
            bf16x8 a[4], b[4];
#pragma unroll
            for (int i = 0; i < 4; ++i)
                a[i] = *(const bf16x8*)(ldsH1 + (arow + i * 16) * H1S + k0 + koff);
#pragma unroll
            for (int j = 0; j < 4; ++j)
                b[j] = *(const bf16x8*)(ldsB + (brow + j * 16) * 32 + koff);
#pragma unroll
            for (int i = 0; i < 4; ++i)
#pragma unroll
                for (int j = 0; j < 4; ++j)
                    acc2[i][j] = __builtin_amdgcn_mfma_f32_16x16x32_bf16(a[i], b[j], acc2[i][j], 0, 0, 0);
        }
        __syncthreads();   // done with ldsH1/ldsB before next nt overwrites
    }

    // ---- h2 -> ldsH2 (relu + bias) ----
#pragma unroll
    for (int i = 0; i < 4; ++i)
#pragma unroll
        for (int j = 0; j < 4; ++j) {
            int col = ccol0 + j * 16;
            float bb = b2[col];
#pragma unroll
            for (int jj = 0; jj < 4; ++jj) {
                int row = crow + i * 16 + jj;
                float v = fmaxf(acc2[i][j][jj] + bb, 0.0f);
                ldsH2[row * H1S + col] = f2bf(v);
            }
        }
    __syncthreads();

    // ---- head: threads 0..127, one row each ----
    if (tid < 128) {
        const unsigned short* hrow = ldsH2 + tid * H1S;
        float accv[7];
#pragma unroll
        for (int cc = 0; cc < 7; ++cc) accv[cc] = ldsB3[cc];
        for (int k = 0; k < 128; ++k) {
            float f = bf2f(hrow[k]);
#pragma unroll
            for (int cc = 0; cc < 7; ++cc)
                accv[cc] = fmaf(f, ldsW3[k * 7 + cc], accv[cc]);
        }
        float mx = accv[0];
#pragma unroll
        for (int cc = 1; cc < 7; ++cc) mx = fmaxf(mx, accv[cc]);
        float sum = 0.f;
#pragma unroll
        for (int cc = 0; cc < 7; ++cc) { accv[cc] = __expf(accv[cc] - mx); sum += accv[cc]; }
        float inv = 1.0f / sum;
#pragma unroll
        for (int cc = 0; cc < 7; ++cc) out[(size_t)(m0 + tid) * 7 + cc] = accv[cc] * inv;
    }
}

// ---------------------------------------------------------------------------
extern "C" void kernel_launch(void* const* d_in, const int* in_sizes, int n_in,
                              void* d_out, int out_size, void* d_ws, size_t ws_size,
                              hipStream_t stream) {
    (void)in_sizes; (void)n_in; (void)out_size; (void)ws_size;
    const float* obj    = (const float*)d_in[0];
    const int*   pairs  = (const int*)  d_in[1];
    const float* fuse_w = (const float*)d_in[2];
    const float* fuse_b = (const float*)d_in[3];
    const float* gcn_w  = (const float*)d_in[4];
    const float* gcn_b  = (const float*)d_in[5];
    const float* fc1_w  = (const float*)d_in[6];
    const float* fc1_b  = (const float*)d_in[7];
    const float* fc2_w  = (const float*)d_in[8];
    const float* fc2_b  = (const float*)d_in[9];
    const float* fc3_w  = (const float*)d_in[10];
    const float* fc3_b  = (const float*)d_in[11];
    float* out = (float*)d_out;

    char* ws = (char*)d_ws;
    unsigned short* As   = (unsigned short*)(ws);                    // 64 MB
    unsigned short* Msum = (unsigned short*)(ws + (64u  << 20));     // 32 MB
    unsigned short* rf   = (unsigned short*)(ws + (96u  << 20));     // 32 MB
    unsigned short* WfT  = (unsigned short*)(ws + (128u << 20));     //  1 MB
    unsigned short* WgT  = (unsigned short*)(ws + (129u << 20));     // 512 KB
    unsigned short* W1T  = (unsigned short*)(ws + (130u << 20));     // 256 KB
    unsigned short* W2T  = (unsigned short*)(ws + (131u << 20));     //  64 KB

    // Stage 0: gather + weight transposes (f32 KxN -> bf16 NxK)
    gather_kernel<<<MTOT / 8, 256, 0, stream>>>(obj, pairs, As, Msum);
    transpose_tile<<<dim3(1024 / 32, 512 / 32), 256, 0, stream>>>(fuse_w, WfT, 1024, 512);
    transpose_tile<<<dim3(512  / 32, 512 / 32), 256, 0, stream>>>(gcn_w,  WgT, 512,  512);
    transpose_tile<<<dim3(512  / 32, 256 / 32), 256, 0, stream>>>(fc1_w,  W1T, 512,  256);
    transpose_tile<<<dim3(256  / 32, 128 / 32), 256, 0, stream>>>(fc2_w,  W2T, 256,  128);

    // Stage 1+2 fused: rf = relu(Msum@gcn_w+gcn_b) + As@fuse_w+fuse_b
    gemm_fused12<<<dim3(MTOT / 128, 4), 256, 0, stream>>>(
        As, Msum, WfT, WgT, fuse_b, gcn_b, rf);

    // Stage 3+4+5 fused: out = softmax(relu(relu(rf@W1+b1)@W2+b2)@W3+b3)
    tail_kernel<<<MTOT / 128, 256, 0, stream>>>(
        rf, W1T, W2T, fc1_b, fc2_b, fc3_w, fc3_b, out);
}

// Round 3
// 447.733 us; speedup vs baseline: 1.1191x; 1.0502x over previous
//
#include <hip/hip_runtime.h>
#include <hip/hip_bf16.h>

// Problem constants
#define B_    1024
#define NOBJ  128
#define RREL  32
#define DIM   512
#define MTOT  32768   // B_*RREL

typedef __bf16 bf16x8 __attribute__((ext_vector_type(8)));
typedef float  f32x4  __attribute__((ext_vector_type(4)));
typedef unsigned short us;

__device__ __forceinline__ us f2bf(float f) {
    unsigned int u = __float_as_uint(f);
    u += 0x7FFFu + ((u >> 16) & 1u);           // round-to-nearest-even
    return (us)(u >> 16);
}
__device__ __forceinline__ float bf2f(us h) {
    return __uint_as_float(((unsigned int)h) << 16);
}

__device__ __forceinline__ void load16_to_lds(const us* g, us* l) {
    // per-lane global address; LDS dest = wave-uniform base + lane*16
    __builtin_amdgcn_global_load_lds((const __attribute__((address_space(1))) void*)g,
                                     (__attribute__((address_space(3))) void*)l,
                                     16, 0, 0);
}

// ---------------------------------------------------------------------------
// Kernel 0: gather rows per relation, emit As=[s;o] bf16 (M x 1024) and
// Msum = bf16(s+o or s) (M x 512). 16B loads, 8B stores.
// ---------------------------------------------------------------------------
__global__ __launch_bounds__(256) void gather_kernel(
        const float* __restrict__ obj, const int* __restrict__ pairs,
        us* __restrict__ As, us* __restrict__ Msum) {
    int t = threadIdx.x;
    int g = t >> 7;          // which relation of the pair
    int c = t & 127;         // float4 chunk within 512-elem row
    int base = blockIdx.x * 8;
#pragma unroll
    for (int rr = 0; rr < 4; ++rr) {
        int m  = base + rr * 2 + g;
        int b  = m >> 5;
        int p0 = pairs[(m << 1) + 0];
        int p1 = pairs[(m << 1) + 1];
        const float4* srow = (const float4*)(obj + (size_t)(b * NOBJ + p0) * DIM);
        const float4* orow = (const float4*)(obj + (size_t)(b * NOBJ + p1) * DIM);
        float4 s4 = srow[c];
        float4 o4 = orow[c];
        size_t arow = (size_t)m * 1024;
        ushort4 sb = make_ushort4(f2bf(s4.x), f2bf(s4.y), f2bf(s4.z), f2bf(s4.w));
        ushort4 ob = make_ushort4(f2bf(o4.x), f2bf(o4.y), f2bf(o4.z), f2bf(o4.w));
        *(ushort4*)(As + arow + c * 4)       = sb;
        *(ushort4*)(As + arow + 512 + c * 4) = ob;
        float4 mz = s4;
        if (p0 != p1) { mz.x += o4.x; mz.y += o4.y; mz.z += o4.z; mz.w += o4.w; }
        *(ushort4*)(Msum + (size_t)m * 512 + c * 4) =
            make_ushort4(f2bf(mz.x), f2bf(mz.y), f2bf(mz.z), f2bf(mz.w));
    }
}

// ---------------------------------------------------------------------------
// Merged weight prep: 4 matrices f32 (K x N) -> bf16 (N x K) in one dispatch.
// 32x32 LDS tile; block id selects the matrix.
// ---------------------------------------------------------------------------
__global__ __launch_bounds__(256) void prep_weights(
        const float* __restrict__ fw, const float* __restrict__ gw,
        const float* __restrict__ w1, const float* __restrict__ w2,
        us* __restrict__ WfT, us* __restrict__ WgT,
        us* __restrict__ W1T, us* __restrict__ W2T) {
    __shared__ float t32[32][33];
    int id = blockIdx.x;
    const float* in; us* out; int K, N, local;
    if (id < 512)      { in = fw; out = WfT; K = 1024; N = 512; local = id; }
    else if (id < 768) { in = gw; out = WgT; K = 512;  N = 512; local = id - 512; }
    else if (id < 896) { in = w1; out = W1T; K = 512;  N = 256; local = id - 768; }
    else               { in = w2; out = W2T; K = 256;  N = 128; local = id - 896; }
    int tilesN = N >> 5;
    int bk = (local / tilesN) * 32;
    int bn = (local % tilesN) * 32;
    int t  = threadIdx.x;
    int tx = t & 31, ty = t >> 5;            // 32 x 8
#pragma unroll
    for (int i = 0; i < 4; ++i)
        t32[ty + i * 8][tx] = in[(size_t)(bk + ty + i * 8) * N + bn + tx];
    __syncthreads();
#pragma unroll
    for (int i = 0; i < 4; ++i)
        out[(size_t)(bn + ty + i * 8) * K + bk + tx] = f2bf(t32[tx][ty + i * 8]);
}

// ---------------------------------------------------------------------------
// Fused stages 1+2:
//   rf = relu(Msum @ gcn_w + gcn_b) + (As @ fuse_w + fuse_b)   -> bf16 (M x 512)
// m97 structure: 128x128 tile, 4 waves 2x2, 4x4 mfma 16x16x32 per wave,
// two accumulator sets (fuse: K=1024, gcn: K=512).
// ---------------------------------------------------------------------------
__global__ __launch_bounds__(256, 2) void gemm_fused12(
        const us* __restrict__ As,   // M x 1024
        const us* __restrict__ Msum, // M x 512
        const us* __restrict__ WfT,  // 512 x 1024 (N x K)
        const us* __restrict__ WgT,  // 512 x 512
        const float* __restrict__ fuse_b, const float* __restrict__ gcn_b,
        us* __restrict__ rf) {
    __shared__ __align__(16) us ldsA[128 * 32];
    __shared__ __align__(16) us ldsB[128 * 32];

    int tid  = threadIdx.x;
    int wid  = tid >> 6;
    int lane = tid & 63;
    int wm   = wid & 1;
    int wn   = wid >> 1;
    int m0   = blockIdx.x * 128;
    int n0   = blockIdx.y * 128;

    f32x4 accF[4][4], accG[4][4];
#pragma unroll
    for (int i = 0; i < 4; ++i)
#pragma unroll
        for (int j = 0; j < 4; ++j)
#pragma unroll
            for (int k = 0; k < 4; ++k) { accF[i][j][k] = 0.0f; accG[i][j][k] = 0.0f; }

    int r = tid >> 2, c = tid & 3;
    us* la0 = ldsA + wid * 512;
    us* la1 = ldsA + 2048 + wid * 512;
    us* lb0 = ldsB + wid * 512;
    us* lb1 = ldsB + 2048 + wid * 512;

    int arow = wm * 64 + (lane & 15);
    int brow = wn * 64 + (lane & 15);
    int koff = (lane >> 4) * 8;

    // ---- phase A: fuse GEMM, K=1024 ----
    {
        const us* ag0 = As + (size_t)(m0 + r)      * 1024 + c * 8;
        const us* ag1 = As + (size_t)(m0 + 64 + r) * 1024 + c * 8;
        const us* bg0 = WfT + (size_t)(n0 + r)      * 1024 + c * 8;
        const us* bg1 = WfT + (size_t)(n0 + 64 + r) * 1024 + c * 8;
        for (int k0 = 0; k0 < 1024; k0 += 32) {
            __syncthreads();
            load16_to_lds(ag0 + k0, la0);
            load16_to_lds(ag1 + k0, la1);
            load16_to_lds(bg0 + k0, lb0);
            load16_to_lds(bg1 + k0, lb1);
            __syncthreads();
            bf16x8 a[4], b[4];
#pragma unroll
            for (int i = 0; i < 4; ++i)
                a[i] = *(const bf16x8*)(ldsA + (arow + i * 16) * 32 + koff);
#pragma unroll
            for (int j = 0; j < 4; ++j)
                b[j] = *(const bf16x8*)(ldsB + (brow + j * 16) * 32 + koff);
#pragma unroll
            for (int i = 0; i < 4; ++i)
#pragma unroll
                for (int j = 0; j < 4; ++j)
                    accF[i][j] = __builtin_amdgcn_mfma_f32_16x16x32_bf16(a[i], b[j], accF[i][j], 0, 0, 0);
        }
    }
    // ---- phase B: gcn GEMM, K=512 ----
    {
        const us* ag0 = Msum + (size_t)(m0 + r)      * 512 + c * 8;
        const us* ag1 = Msum + (size_t)(m0 + 64 + r) * 512 + c * 8;
        const us* bg0 = WgT + (size_t)(n0 + r)      * 512 + c * 8;
        const us* bg1 = WgT + (size_t)(n0 + 64 + r) * 512 + c * 8;
        for (int k0 = 0; k0 < 512; k0 += 32) {
            __syncthreads();
            load16_to_lds(ag0 + k0, la0);
            load16_to_lds(ag1 + k0, la1);
            load16_to_lds(bg0 + k0, lb0);
            load16_to_lds(bg1 + k0, lb1);
            __syncthreads();
            bf16x8 a[4], b[4];
#pragma unroll
            for (int i = 0; i < 4; ++i)
                a[i] = *(const bf16x8*)(ldsA + (arow + i * 16) * 32 + koff);
#pragma unroll
            for (int j = 0; j < 4; ++j)
                b[j] = *(const bf16x8*)(ldsB + (brow + j * 16) * 32 + koff);
#pragma unroll
            for (int i = 0; i < 4; ++i)
#pragma unroll
                for (int j = 0; j < 4; ++j)
                    accG[i][j] = __builtin_amdgcn_mfma_f32_16x16x32_bf16(a[i], b[j], accG[i][j], 0, 0, 0);
        }
    }

    // epilogue: C/D layout col = lane&15, row = (lane>>4)*4 + reg
    int crow  = wm * 64 + (lane >> 4) * 4;
    int ccol0 = wn * 64 + (lane & 15);
    float bf_[4], bg_[4];
#pragma unroll
    for (int j = 0; j < 4; ++j) {
        bf_[j] = fuse_b[n0 + ccol0 + j * 16];
        bg_[j] = gcn_b [n0 + ccol0 + j * 16];
    }
#pragma unroll
    for (int i = 0; i < 4; ++i)
#pragma unroll
        for (int j = 0; j < 4; ++j) {
            int col = n0 + ccol0 + j * 16;
#pragma unroll
            for (int jj = 0; jj < 4; ++jj) {
                int row = m0 + crow + i * 16 + jj;
                float v = fmaxf(accG[i][j][jj] + bg_[j], 0.0f) + accF[i][j][jj] + bf_[j];
                rf[(size_t)row * 512 + col] = f2bf(v);
            }
        }
}

// ---------------------------------------------------------------------------
// Fused tail, 64-row blocks (512 blocks -> 2 blocks/CU):
//   h1 = relu(rf@W1+b1); h2 = relu(h1@W2+b2); out = softmax(h2@W3+b3)
// fc1: 4 waves across N=256 (64 cols each). fc2: 2x2 (N-half x K-half) with
// cross-wave f32 reduction through LDS. Head: 4 threads/row + shfl_xor.
// LDS overlay: H2 over stage region, red over dead H1. Total ~57.9 KB.
// ---------------------------------------------------------------------------
#define H1S 264   // shorts (132 floats) per row, pad 8
#define H2S 136
__global__ __launch_bounds__(256, 2) void tail_kernel(
        const us* __restrict__ rf,   // M x 512
        const us* __restrict__ W1T,  // 256 x 512 (N x K)
        const us* __restrict__ W2T,  // 128 x 256
        const float* __restrict__ b1, const float* __restrict__ b2,
        const float* __restrict__ w3, const float* __restrict__ b3,
        float* __restrict__ out) {
    __shared__ __align__(16) unsigned char pool[57888];
    us*    sA   = (us*)(pool);            //  4 KB: A stage 64x32
    us*    sB   = (us*)(pool + 4096);     // 16 KB: B stage (256x32 or 2x128x32)
    us*    sH2  = (us*)(pool);            // 17 KB overlay on stage (h2 64x136)
    us*    sH1  = (us*)(pool + 20480);    // 33.8 KB: h1 64x264
    float* sRed = (float*)(pool + 20480); // overlay: fc2 partials 64x132
    float* sW3  = (float*)(pool + 54272); // 3.5 KB
    float* sB3  = (float*)(pool + 57856);

    int tid  = threadIdx.x;
    int wid  = tid >> 6;
    int lane = tid & 63;
    int m0   = blockIdx.x * 64;

    for (int i = tid; i < 128 * 7; i += 256) sW3[i] = w3[i];
    if (tid < 7) sB3[tid] = b3[tid];

    int r = tid >> 2, c = tid & 3;        // staging role: row r (0..63), chunk c
    int koff = (lane >> 4) * 8;
    int l15  = lane & 15;

    // ================= fc1: C1[64x256] = rf[64x512] @ W1T^T =================
    f32x4 acc1[4][4];
#pragma unroll
    for (int i = 0; i < 4; ++i)
#pragma unroll
        for (int j = 0; j < 4; ++j)
#pragma unroll
            for (int k = 0; k < 4; ++k) acc1[i][j][k] = 0.0f;

    {
        const us* ag = rf + (size_t)(m0 + r) * 512 + c * 8;
        us* la = sA + wid * 512;
        for (int k0 = 0; k0 < 512; k0 += 32) {
            __syncthreads();
            load16_to_lds(ag + k0, la);
#pragma unroll
            for (int q = 0; q < 4; ++q)
                load16_to_lds(W1T + (size_t)(q * 64 + r) * 512 + k0 + c * 8,
                              sB + q * 2048 + wid * 512);
            __syncthreads();
            bf16x8 a[4], b[4];
#pragma unroll
            for (int i = 0; i < 4; ++i)
                a[i] = *(const bf16x8*)(sA + (l15 + i * 16) * 32 + koff);
#pragma unroll
            for (int j = 0; j < 4; ++j)
                b[j] = *(const bf16x8*)(sB + (wid * 64 + j * 16 + l15) * 32 + koff);
#pragma unroll
            for (int i = 0; i < 4; ++i)
#pragma unroll
                for (int j = 0; j < 4; ++j)
                    acc1[i][j] = __builtin_amdgcn_mfma_f32_16x16x32_bf16(a[i], b[j], acc1[i][j], 0, 0, 0);
        }
    }
    // epilogue fc1 -> sH1 (relu + bias); wave wid owns cols wid*64..+64
#pragma unroll
    for (int i = 0; i < 4; ++i)
#pragma unroll
        for (int j = 0; j < 4; ++j) {
            int col = wid * 64 + j * 16 + l15;
            float bb = b1[col];
#pragma unroll
            for (int jj = 0; jj < 4; ++jj) {
                int row = i * 16 + (lane >> 4) * 4 + jj;
                sH1[row * H1S + col] = f2bf(fmaxf(acc1[i][j][jj] + bb, 0.0f));
            }
        }

    // ================= fc2: C2[64x128] = H1[64x256] @ W2T^T =================
    // wave (kw = wid>>1, nw = wid&1): K-half kw, N-half nw (64 cols)
    int nw = wid & 1, kw = wid >> 1;
    f32x4 acc2[4][4];
#pragma unroll
    for (int i = 0; i < 4; ++i)
#pragma unroll
        for (int j = 0; j < 4; ++j)
#pragma unroll
            for (int k = 0; k < 4; ++k) acc2[i][j][k] = 0.0f;

    for (int t = 0; t < 4; ++t) {
        __syncthreads();     // also makes sH1 visible on t==0
#pragma unroll
        for (int s = 0; s < 2; ++s)
#pragma unroll
            for (int q = 0; q < 2; ++q)
                load16_to_lds(W2T + (size_t)(q * 64 + r) * 256 + s * 128 + t * 32 + c * 8,
                              sB + s * 4096 + q * 2048 + wid * 512);
        __syncthreads();
        bf16x8 a[4], b[4];
#pragma unroll
        for (int i = 0; i < 4; ++i)
            a[i] = *(const bf16x8*)(sH1 + (l15 + i * 16) * H1S + kw * 128 + t * 32 + koff);
#pragma unroll
        for (int j = 0; j < 4; ++j)
            b[j] = *(const bf16x8*)(sB + kw * 4096 + (nw * 64 + j * 16 + l15) * 32 + koff);
#pragma unroll
        for (int i = 0; i < 4; ++i)
#pragma unroll
            for (int j = 0; j < 4; ++j)
                acc2[i][j] = __builtin_amdgcn_mfma_f32_16x16x32_bf16(a[i], b[j], acc2[i][j], 0, 0, 0);
    }
    __syncthreads();                       // H1 reads done; red may overwrite
    if (kw == 1) {                         // write partials (overlay on H1)
#pragma unroll
        for (int i = 0; i < 4; ++i)
#pragma unroll
            for (int j = 0; j < 4; ++j) {
                int col = nw * 64 + j * 16 + l15;
#pragma unroll
                for (int jj = 0; jj < 4; ++jj) {
                    int row = i * 16 + (lane >> 4) * 4 + jj;
                    sRed[row * 132 + col] = acc2[i][j][jj];
                }
            }
    }
    __syncthreads();
    if (kw == 0) {                         // combine, relu, h2 -> sH2
#pragma unroll
        for (int i = 0; i < 4; ++i)
#pragma unroll
            for (int j = 0; j < 4; ++j) {
                int col = nw * 64 + j * 16 + l15;
                float bb = b2[col];
#pragma unroll
                for (int jj = 0; jj < 4; ++jj) {
                    int row = i * 16 + (lane >> 4) * 4 + jj;
                    float v = acc2[i][j][jj] + sRed[row * 132 + col] + bb;
                    sH2[row * H2S + col] = f2bf(fmaxf(v, 0.0f));
                }
            }
    }
    __syncthreads();

    // ================= head: 4 threads per row, shfl combine ================
    int row = tid >> 2;          // 0..63
    int p   = tid & 3;           // K quarter
    float accv[7];
#pragma unroll
    for (int cc = 0; cc < 7; ++cc) accv[cc] = 0.0f;
    const us* hrow = sH2 + row * H2S + p * 32;
    for (int kk = 0; kk < 8; ++kk) {
        ushort4 u = *(const ushort4*)(hrow + kk * 4);
        float f0 = bf2f(u.x), f1 = bf2f(u.y), f2 = bf2f(u.z), f3 = bf2f(u.w);
        int k = p * 32 + kk * 4;
#pragma unroll
        for (int cc = 0; cc < 7; ++cc) {
            accv[cc] = fmaf(f0, sW3[(k + 0) * 7 + cc], accv[cc]);
            accv[cc] = fmaf(f1, sW3[(k + 1) * 7 + cc], accv[cc]);
            accv[cc] = fmaf(f2, sW3[(k + 2) * 7 + cc], accv[cc]);
            accv[cc] = fmaf(f3, sW3[(k + 3) * 7 + cc], accv[cc]);
        }
    }
#pragma unroll
    for (int cc = 0; cc < 7; ++cc) {
        accv[cc] += __shfl_xor(accv[cc], 1);
        accv[cc] += __shfl_xor(accv[cc], 2);
    }
    if (p == 0) {
        float mx = accv[0] + sB3[0];
        float lg[7];
#pragma unroll
        for (int cc = 0; cc < 7; ++cc) { lg[cc] = accv[cc] + sB3[cc]; mx = fmaxf(mx, lg[cc]); }
        float sum = 0.f;
#pragma unroll
        for (int cc = 0; cc < 7; ++cc) { lg[cc] = __expf(lg[cc] - mx); sum += lg[cc]; }
        float inv = 1.0f / sum;
#pragma unroll
        for (int cc = 0; cc < 7; ++cc) out[(size_t)(m0 + row) * 7 + cc] = lg[cc] * inv;
    }
}

// ---------------------------------------------------------------------------
extern "C" void kernel_launch(void* const* d_in, const int* in_sizes, int n_in,
                              void* d_out, int out_size, void* d_ws, size_t ws_size,
                              hipStream_t stream) {
    (void)in_sizes; (void)n_in; (void)out_size; (void)ws_size;
    const float* obj    = (const float*)d_in[0];
    const int*   pairs  = (const int*)  d_in[1];
    const float* fuse_w = (const float*)d_in[2];
    const float* fuse_b = (const float*)d_in[3];
    const float* gcn_w  = (const float*)d_in[4];
    const float* gcn_b  = (const float*)d_in[5];
    const float* fc1_w  = (const float*)d_in[6];
    const float* fc1_b  = (const float*)d_in[7];
    const float* fc2_w  = (const float*)d_in[8];
    const float* fc2_b  = (const float*)d_in[9];
    const float* fc3_w  = (const float*)d_in[10];
    const float* fc3_b  = (const float*)d_in[11];
    float* out = (float*)d_out;

    char* ws = (char*)d_ws;
    us* As   = (us*)(ws);                    // 64 MB
    us* Msum = (us*)(ws + (64u  << 20));     // 32 MB
    us* rf   = (us*)(ws + (96u  << 20));     // 32 MB
    us* WfT  = (us*)(ws + (128u << 20));     //  1 MB
    us* WgT  = (us*)(ws + (129u << 20));     // 512 KB
    us* W1T  = (us*)(ws + (130u << 20));     // 256 KB
    us* W2T  = (us*)(ws + (131u << 20));     //  64 KB

    // Stage 0: gather + merged weight transposes (f32 KxN -> bf16 NxK)
    gather_kernel<<<MTOT / 8, 256, 0, stream>>>(obj, pairs, As, Msum);
    prep_weights<<<928, 256, 0, stream>>>(fuse_w, gcn_w, fc1_w, fc2_w,
                                          WfT, WgT, W1T, W2T);

    // Stage 1+2 fused: rf = relu(Msum@gcn_w+gcn_b) + As@fuse_w+fuse_b
    gemm_fused12<<<dim3(MTOT / 128, 4), 256, 0, stream>>>(
        As, Msum, WfT, WgT, fuse_b, gcn_b, rf);

    // Stage 3+4+5 fused: out = softmax(relu(relu(rf@W1+b1)@W2+b2)@W3+b3)
    tail_kernel<<<MTOT / 64, 256, 0, stream>>>(
        rf, W1T, W2T, fc1_b, fc2_b, fc3_w, fc3_b, out);
}